// Round 5
// baseline (95.239 us; speedup 1.0000x reference)
//
#include <hip/hip_runtime.h>
#include <hip/hip_bf16.h>

#define NPTS 4096
#define NROWS 8192   // B*N
#define DIM 128
#define CAP 8        // per-(row,half) hit buffer; hits = 4 + ties <= 8 unless 5+-way tie

typedef __attribute__((ext_vector_type(8))) short bf16x8;
typedef __attribute__((ext_vector_type(4))) float f32x4;

// ---------- prep: pos -> float4[8192], W -> W^T bf16 (verified) ----------
__global__ __launch_bounds__(256) void prep(const float* __restrict__ pos,
                                            const float* __restrict__ W,
                                            float4* __restrict__ pos4,
                                            __hip_bfloat16* __restrict__ Wt) {
    int t = blockIdx.x * 256 + threadIdx.x;
    if (t < NROWS) {
        const float* p = pos + (size_t)t * 3;
        pos4[t] = make_float4(p[0], p[1], p[2], 0.f);
    } else if (t < NROWS + DIM * DIM) {
        int i = t - NROWS;
        int n = i >> 7, k = i & 127;
        Wt[i] = __float2bfloat16(W[k * DIM + n]);  // Wt[n][k] = W[k][n]
    }
}

// ---------- xW = x @ W via bf16 MFMA, output bf16 (verified) ----------
__global__ __launch_bounds__(256) void xw_mfma(const float* __restrict__ x,
                                               const __hip_bfloat16* __restrict__ Wt,
                                               __hip_bfloat16* __restrict__ xWb) {
    int wave = threadIdx.x >> 6;
    int lane = threadIdx.x & 63;
    int tile = blockIdx.x * 4 + wave;          // 0..4095
    int m0 = (tile >> 3) << 4;
    int n0 = (tile & 7) << 4;
    int r = lane & 15;
    int kg = lane >> 4;                        // 0..3
    const float* xr = x + (size_t)(m0 + r) * DIM + kg * 8;
    const __hip_bfloat16* br = Wt + (size_t)(n0 + r) * DIM + kg * 8;
    f32x4 acc = {0.f, 0.f, 0.f, 0.f};
#pragma unroll
    for (int kb = 0; kb < 4; ++kb) {
        float4 a0 = *(const float4*)(xr + kb * 32);
        float4 a1 = *(const float4*)(xr + kb * 32 + 4);
        bf16x8 af;
        union { __hip_bfloat16 h; short s; } u;
        u.h = __float2bfloat16(a0.x); af[0] = u.s;
        u.h = __float2bfloat16(a0.y); af[1] = u.s;
        u.h = __float2bfloat16(a0.z); af[2] = u.s;
        u.h = __float2bfloat16(a0.w); af[3] = u.s;
        u.h = __float2bfloat16(a1.x); af[4] = u.s;
        u.h = __float2bfloat16(a1.y); af[5] = u.s;
        u.h = __float2bfloat16(a1.z); af[6] = u.s;
        u.h = __float2bfloat16(a1.w); af[7] = u.s;
        bf16x8 bfr = *(const bf16x8*)(br + kb * 32);
        acc = __builtin_amdgcn_mfma_f32_16x16x32_bf16(af, bfr, acc, 0, 0, 0);
    }
    int col = n0 + r;
    int rbase = m0 + (kg << 2);
#pragma unroll
    for (int reg = 0; reg < 4; ++reg)
        xWb[(size_t)(rbase + reg) * DIM + col] = __float2bfloat16(acc[reg]);
}

// Bit-identical d^2 for pass 1 and pass 2 (same codegen => same rounding).
__device__ __forceinline__ float dist2(float4 q, float4 p) {
    float dx = q.x - p.x, dy = q.y - p.y, dz = q.z - p.z;
    return fmaf(dx, dx, fmaf(dy, dy, dz * dz));
}

// sorted-ascending insert of s into (k0<=k1<=k2<=k3): 7 v_min/max_f32
__device__ __forceinline__ void vins(float& k0, float& k1, float& k2, float& k3,
                                     float s) {
    float c = fmaxf(k0, s); k0 = fminf(k0, s);
    float t = fmaxf(k1, c); k1 = fminf(k1, c); c = t;
    t = fmaxf(k2, c);       k2 = fminf(k2, c); c = t;
    k3 = fminf(k3, c);
}

// merge two sorted-asc 4-lists -> 4 smallest sorted: 12 v_min/max_f32
__device__ __forceinline__ void vmerge(float& a0, float& a1, float& a2, float& a3,
                                       float b0, float b1, float b2, float b3) {
    float m0 = fminf(a0, b3), m1 = fminf(a1, b2);
    float m2 = fminf(a2, b1), m3 = fminf(a3, b0);
    float t0 = fminf(m0, m2), t2 = fmaxf(m0, m2);
    float t1 = fminf(m1, m3), t3 = fmaxf(m1, m3);
    a0 = fminf(t0, t1); a1 = fmaxf(t0, t1);
    a2 = fminf(t2, t3); a3 = fmaxf(t2, t3);
}

// 4 waves/block: group = wave>>1 owns rows (2g, 2g+1); half = wave&1 scans
// 2048 candidates. Pass1: f32 value-only top4. Pass2: threshold rescan ->
// LDS hit list. Finalize: exact f64 (d2|j) rank over <=16 hits.
__global__ __launch_bounds__(256, 8) void topk_agg(const float4* __restrict__ pos4,
                                                   const __hip_bfloat16* __restrict__ xWb,
                                                   const float* __restrict__ bias,
                                                   float* __restrict__ out) {
    int lane = threadIdx.x & 63;
    int wave = threadIdx.x >> 6;
    int group = wave >> 1;
    int half = wave & 1;
    int rowbase = blockIdx.x * 4 + group * 2;   // 4 rows/block
    int batch = rowbase >> 12;
    int ibase = rowbase & (NPTS - 1);
    const float4* pb = pos4 + (size_t)batch * NPTS;

    __shared__ float    vx[2][2][2][4];        // [group][half][row][slot]
    __shared__ unsigned hidx[2][2][2][CAP];    // [group][row][half][slot]
    __shared__ float    hdva[2][2][2][CAP];
    __shared__ unsigned hcnt[2][2][2];
    __shared__ unsigned fidx[2][2][4];         // [group][row][rank]
    __shared__ float    fdst[2][2][4];

    float4 q0 = pb[ibase], q1 = pb[ibase + 1];
    const float INF = __int_as_float(0x7f800000);
    float a0 = INF, a1 = INF, a2 = INF, a3 = INF;   // row 0 values
    float b0 = INF, b1 = INF, b2 = INF, b3 = INF;   // row 1 values
    int jbase = (half << 11) + lane;

    // ---- pass 1: f32 value-only scan ----
#pragma unroll 4
    for (int t = 0; t < 32; ++t) {
        float4 p = pb[jbase + (t << 6)];
        vins(a0, a1, a2, a3, dist2(q0, p));
        vins(b0, b1, b2, b3, dist2(q1, p));
    }
    // intra-wave butterfly
#pragma unroll
    for (int off = 1; off < 64; off <<= 1) {
        float p0 = __shfl_xor(a0, off), p1 = __shfl_xor(a1, off);
        float p2 = __shfl_xor(a2, off), p3 = __shfl_xor(a3, off);
        vmerge(a0, a1, a2, a3, p0, p1, p2, p3);
        p0 = __shfl_xor(b0, off); p1 = __shfl_xor(b1, off);
        p2 = __shfl_xor(b2, off); p3 = __shfl_xor(b3, off);
        vmerge(b0, b1, b2, b3, p0, p1, p2, p3);
    }
    // cross-half value merge (symmetric: sorted values unique regardless of order)
    if (lane == 0) {
        vx[group][half][0][0] = a0; vx[group][half][0][1] = a1;
        vx[group][half][0][2] = a2; vx[group][half][0][3] = a3;
        vx[group][half][1][0] = b0; vx[group][half][1][1] = b1;
        vx[group][half][1][2] = b2; vx[group][half][1][3] = b3;
    }
    __syncthreads();
    {
        int oh = half ^ 1;
        vmerge(a0, a1, a2, a3, vx[group][oh][0][0], vx[group][oh][0][1],
                               vx[group][oh][0][2], vx[group][oh][0][3]);
        vmerge(b0, b1, b2, b3, vx[group][oh][1][0], vx[group][oh][1][1],
                               vx[group][oh][1][2], vx[group][oh][1][3]);
    }
    float t3a = a3, t3b = b3;   // exact global 4th-smallest d2 per row

    // ---- pass 2: threshold rescan -> hit lists (no atomics) ----
    unsigned ca = 0, cb = 0;    // wave-uniform running counts
#pragma unroll 2
    for (int t = 0; t < 32; ++t) {
        int j = jbase + (t << 6);
        float4 p = pb[j];
        float da = dist2(q0, p);
        float db = dist2(q1, p);
        bool ha = da <= t3a;
        unsigned long long ma = __ballot(ha);
        if (ma) {
            if (ha) {
                unsigned posn = ca + (unsigned)__popcll(ma & ((1ull << lane) - 1));
                if (posn < CAP) { hidx[group][0][half][posn] = (unsigned)j;
                                  hdva[group][0][half][posn] = da; }
            }
            ca += (unsigned)__popcll(ma);
        }
        bool hb = db <= t3b;
        unsigned long long mb = __ballot(hb);
        if (mb) {
            if (hb) {
                unsigned posn = cb + (unsigned)__popcll(mb & ((1ull << lane) - 1));
                if (posn < CAP) { hidx[group][1][half][posn] = (unsigned)j;
                                  hdva[group][1][half][posn] = db; }
            }
            cb += (unsigned)__popcll(mb);
        }
    }
    if (lane == 0) {
        hcnt[group][0][half] = ca < CAP ? ca : CAP;
        hcnt[group][1][half] = cb < CAP ? cb : CAP;
    }
    __syncthreads();

    // ---- finalize: exact (f64 d2 | j) rank over <=16 hits ----
    if (half == 0 && lane < 32) {
        int r = lane >> 4;       // lanes 0-15: row 0, lanes 16-31: row 1
        int e = lane & 15;
        unsigned c0 = hcnt[group][r][0], c1 = hcnt[group][r][1];
        bool valid = (e < CAP) ? ((unsigned)e < c0) : ((unsigned)(e - CAP) < c1);
        unsigned jj = 0; float dd = 0.f;
        if (valid) {
            jj = hidx[group][r][e >= CAP][e & (CAP - 1)];
            dd = hdva[group][r][e >= CAP][e & (CAP - 1)];
        }
        double key = valid
            ? __longlong_as_double(__double_as_longlong((double)dd) |
                                   (unsigned long long)jj)
            : __builtin_inf();
        int base = lane & 16;    // 16-lane group base (0 or 16)
        int rank = 0;
#pragma unroll
        for (int s = 0; s < 16; ++s) {
            double ks = __shfl(key, base + s);
            rank += (ks < key) ? 1 : 0;
        }
        if (valid && rank < 4) {
            fidx[group][r][rank] = jj;
            fdst[group][r][rank] = dd;
        }
    }
    __syncthreads();
    if (half) return;

    // ---- epilogue: lane owns channels (2*lane, 2*lane+1) ----
    int c = lane << 1;
    float2 bb = *(const float2*)(bias + c);
    const unsigned short* xu = (const unsigned short*)xWb;
    size_t bbase = ((size_t)batch * NPTS) << 7;
#pragma unroll
    for (int k = 0; k < 2; ++k) {
        unsigned i0 = fidx[group][k][0], i1 = fidx[group][k][1];
        unsigned i2 = fidx[group][k][2], i3 = fidx[group][k][3];
        float d0 = fdst[group][k][0], d1 = fdst[group][k][1];
        float d2 = fdst[group][k][2], d3 = fdst[group][k][3];
        float w0 = __expf(-(d0 + 1e-8f) * 0.5f);
        float w1 = __expf(-(d1 + 1e-8f) * 0.5f);
        float w2 = __expf(-(d2 + 1e-8f) * 0.5f);
        float w3 = __expf(-(d3 + 1e-8f) * 0.5f);
        float inv = 1.0f / (w0 + w1 + w2 + w3 + 1e-8f);
        w0 *= inv; w1 *= inv; w2 *= inv; w3 *= inv;
        ushort2 g0 = *(const ushort2*)(xu + bbase + ((size_t)i0 << 7) + c);
        ushort2 g1 = *(const ushort2*)(xu + bbase + ((size_t)i1 << 7) + c);
        ushort2 g2 = *(const ushort2*)(xu + bbase + ((size_t)i2 << 7) + c);
        ushort2 g3 = *(const ushort2*)(xu + bbase + ((size_t)i3 << 7) + c);
        float ox = bb.x + w0 * __uint_as_float((unsigned)g0.x << 16)
                        + w1 * __uint_as_float((unsigned)g1.x << 16)
                        + w2 * __uint_as_float((unsigned)g2.x << 16)
                        + w3 * __uint_as_float((unsigned)g3.x << 16);
        float oy = bb.y + w0 * __uint_as_float((unsigned)g0.y << 16)
                        + w1 * __uint_as_float((unsigned)g1.y << 16)
                        + w2 * __uint_as_float((unsigned)g2.y << 16)
                        + w3 * __uint_as_float((unsigned)g3.y << 16);
        *(float2*)(out + (((size_t)(rowbase + k)) << 7) + c) = make_float2(ox, oy);
    }
}

extern "C" void kernel_launch(void* const* d_in, const int* in_sizes, int n_in,
                              void* d_out, int out_size, void* d_ws, size_t ws_size,
                              hipStream_t stream) {
    const float* x    = (const float*)d_in[0];  // [2,4096,128]
    const float* pos  = (const float*)d_in[1];  // [2,4096,3]
    const float* W    = (const float*)d_in[2];  // [128,128]
    const float* bias = (const float*)d_in[3];  // [128]
    float* out = (float*)d_out;                 // [2,4096,128] f32

    char* ws = (char*)d_ws;
    __hip_bfloat16* xWb = (__hip_bfloat16*)ws;                       // 2 MB
    float4* pos4 = (float4*)(ws + (size_t)NROWS * DIM * 2);          // 128 KB
    __hip_bfloat16* Wt = (__hip_bfloat16*)(ws + (size_t)NROWS * DIM * 2
                                              + (size_t)NROWS * 16); // 32 KB

    prep<<<(NROWS + DIM * DIM + 255) / 256, 256, 0, stream>>>(pos, W, pos4, Wt);
    xw_mfma<<<(NROWS / 16) * (DIM / 16) / 4, 256, 0, stream>>>(x, Wt, xWb);
    topk_agg<<<NROWS / 4, 256, 0, stream>>>(pos4, xWb, bias, out);
}